// Round 9
// baseline (387.592 us; speedup 1.0000x reference)
//
#include <hip/hip_runtime.h>
#include <math.h>

#define DC_C 6
#define NRANGE 8          // slot ranges, aligned to blockIdx%8 -> XCD round-robin
#define VCH 2048          // vars per block-chunk in build_b

// clang ext_vector types: __builtin_nontemporal_load/store requires scalar,
// pointer, or ext_vector pointees (HIP_vector_type wrappers are rejected).
typedef unsigned int       euint4 __attribute__((ext_vector_type(4)));
typedef unsigned int       euint2 __attribute__((ext_vector_type(2)));
typedef float              efloat4 __attribute__((ext_vector_type(4)));
typedef unsigned long long eull2 __attribute__((ext_vector_type(2)));

// Per-check compressed message record: 3 words per check.
// word0 = bits(Asp) = sprod*(relu(min2-b)-a)  [value on argmin edges]
// word1 = bits(Bsp) = sprod*(relu(min1-b)-a)  [value on other edges]
// word2 = masks: bits 0-5 amin, 8-13 negative-sign, 16-21 zero-sign
// c2v_j = sg_j * (amin_j ? Asp : Bsp), sg_j in {+1,-1,0}.

__device__ __forceinline__ float c2v_from_words(unsigned int aw, unsigned int bw,
                                                unsigned int mk, int j) {
    float val = ((mk >> j) & 1u) ? __uint_as_float(aw) : __uint_as_float(bw);
    float s = ((mk >> (16 + j)) & 1u) ? 0.0f
            : (((mk >> (8 + j)) & 1u) ? -1.0f : 1.0f);
    return s * val;
}

// Phase A: slot assignment (nibble-packed counters: 8 checks/word, 4b each;
// count <= 6 so nibbles never carry). 1.57M device atomics ~= 26 G/s floor.
__global__ void build_a(const int* __restrict__ edge_chk,
                        unsigned int* __restrict__ cnt8,
                        unsigned long long* __restrict__ pos64,
                        int n) {
    int v = blockIdx.x * blockDim.x + threadIdx.x;
    if (v >= n) return;
    int c0 = edge_chk[v * 3 + 0];
    int c1 = edge_chk[v * 3 + 1];
    int c2 = edge_chk[v * 3 + 2];
    unsigned int sh0 = (c0 & 7) * 4, sh1 = (c1 & 7) * 4, sh2 = (c2 & 7) * 4;
    unsigned int o0 = atomicAdd(&cnt8[c0 >> 3], 1u << sh0);
    unsigned int o1 = atomicAdd(&cnt8[c1 >> 3], 1u << sh1);
    unsigned int o2 = atomicAdd(&cnt8[c2 >> 3], 1u << sh2);
    int j0 = (o0 >> sh0) & 0xF;
    int j1 = (o1 >> sh1) & 0xF;
    int j2 = (o2 >> sh2) & 0xF;
    unsigned long long s0 = (unsigned long long)(c0 * DC_C + j0);
    unsigned long long s1 = (unsigned long long)(c1 * DC_C + j1);
    unsigned long long s2 = (unsigned long long)(c2 * DC_C + j2);
    pos64[v] = s0 | (s1 << 21) | (s2 << 42);
}

// Phase B: invert pos64 -> vmap (slot -> variable). Only random write in the
// pipeline; range-partitioned so each vmap line is filled from one XCD
// (blockIdx%8 heuristic; perf-only, correctness-independent).
__global__ void build_b(const unsigned long long* __restrict__ pos64,
                        int* __restrict__ vmap,
                        int n, int E) {
    int r = blockIdx.x & (NRANGE - 1);
    int chunk = blockIdx.x >> 3;
    int lo = r * (E / NRANGE);
    int hi = lo + (E / NRANGE);
    int base = chunk * VCH;
#pragma unroll
    for (int rr = 0; rr < VCH / 256; ++rr) {
        int v = base + rr * 256 + threadIdx.x;
        if (v >= n) break;
        unsigned long long pk = pos64[v];
        int s0 = (int)(pk & 0x1FFFFF);
        int s1 = (int)((pk >> 21) & 0x1FFFFF);
        int s2 = (int)((pk >> 42) & 0x1FFFFF);
        if (s0 >= lo && s0 < hi) vmap[s0] = v;
        if (s1 >= lo && s1 < hi) vmap[s1] = v;
        if (s2 >= lo && s2 < hi) vmap[s2] = v;
    }
}

// Check-node update, 2 checks/thread (12 p-gathers in flight).
// Streamed-once data (vmap, recs) uses non-temporal hints to keep L2 for p.
__global__ __launch_bounds__(128) void check_kernel(
        const float* __restrict__ p,        // llr at t=0
        const euint4* __restrict__ vmap4,   // 12 ints / pair = 3x euint4
        euint2* __restrict__ recs2,         // 6 words / pair = 3x euint2
        const float* __restrict__ beta,
        const float* __restrict__ alpha,
        int t, int n_chk2, int first) {
    int i = blockIdx.x * 128 + threadIdx.x;     // pair index
    if (i >= n_chk2) return;
    euint4 w0 = __builtin_nontemporal_load(&vmap4[i * 3 + 0]);
    euint4 w1 = __builtin_nontemporal_load(&vmap4[i * 3 + 1]);
    euint4 w2 = __builtin_nontemporal_load(&vmap4[i * 3 + 2]);
    unsigned int w[12] = {w0.x, w0.y, w0.z, w0.w,
                          w1.x, w1.y, w1.z, w1.w,
                          w2.x, w2.y, w2.z, w2.w};
    float pv[12];
#pragma unroll
    for (int j = 0; j < 12; ++j) pv[j] = p[w[j]];

    float old_[12];
    if (first) {
#pragma unroll
        for (int j = 0; j < 12; ++j) old_[j] = 0.0f;
    } else {
        euint2 r01 = __builtin_nontemporal_load(&recs2[i * 3 + 0]);
        euint2 r23 = __builtin_nontemporal_load(&recs2[i * 3 + 1]);
        euint2 r45 = __builtin_nontemporal_load(&recs2[i * 3 + 2]);
        // rec A = (r01.x, r01.y, r23.x); rec B = (r23.y, r45.x, r45.y)
#pragma unroll
        for (int j = 0; j < DC_C; ++j) {
            old_[j]     = c2v_from_words(r01.x, r01.y, r23.x, j);
            old_[6 + j] = c2v_from_words(r23.y, r45.x, r45.y, j);
        }
    }

    float b = beta[t];
    float a = alpha[t];
    unsigned int rw[6];
#pragma unroll
    for (int h = 0; h < 2; ++h) {
        float sprod = 1.0f;
        float m1 = INFINITY, m2 = INFINITY;
        float mg[DC_C];
        unsigned int ng = 0, zr = 0;
#pragma unroll
        for (int j = 0; j < DC_C; ++j) {
            float x = pv[h * 6 + j] - old_[h * 6 + j];
            float m = fabsf(x);
            mg[j] = m;
            if (x < 0.0f) { ng |= (1u << j); sprod = -sprod; }
            else if (x == 0.0f) { zr |= (1u << j); sprod = 0.0f; }
            if (m < m1) { m2 = m1; m1 = m; }
            else if (m < m2) { m2 = m; }
        }
        unsigned int am = 0;
#pragma unroll
        for (int j = 0; j < DC_C; ++j) am |= (mg[j] == m1) ? (1u << j) : 0u;
        // ties: multiple amin bits imply m2==m1 -> A==B, identical to the
        // reference's first-argmin rule.
        float A = fmaxf(m2 - b, 0.0f) - a;
        float B = fmaxf(m1 - b, 0.0f) - a;
        rw[h * 3 + 0] = __float_as_uint(sprod * A);
        rw[h * 3 + 1] = __float_as_uint(sprod * B);
        rw[h * 3 + 2] = am | (ng << 8) | (zr << 16);
    }
    euint2 s0; s0.x = rw[0]; s0.y = rw[1];
    euint2 s1; s1.x = rw[2]; s1.y = rw[3];
    euint2 s2; s2.x = rw[4]; s2.y = rw[5];
    __builtin_nontemporal_store(s0, &recs2[i * 3 + 0]);
    __builtin_nontemporal_store(s1, &recs2[i * 3 + 1]);
    __builtin_nontemporal_store(s2, &recs2[i * 3 + 2]);
}

// Variable-node update, 4 vars/thread (12 rec-gathers in flight).
// recs viewed as uint3 (12B, dwordx3 gather); streams use NT hints.
__global__ __launch_bounds__(128) void var_kernel(
        const uint3* __restrict__ recs3,
        const eull2* __restrict__ pos64x2,
        const efloat4* __restrict__ llr4,
        efloat4* __restrict__ p4,
        int n4) {
    int i = blockIdx.x * 128 + threadIdx.x;
    if (i >= n4) return;
    eull2 pk01 = __builtin_nontemporal_load(&pos64x2[i * 2 + 0]);
    eull2 pk23 = __builtin_nontemporal_load(&pos64x2[i * 2 + 1]);
    efloat4 ll = __builtin_nontemporal_load(&llr4[i]);
    unsigned long long pk[4] = {pk01.x, pk01.y, pk23.x, pk23.y};
    float tot[4];
#pragma unroll
    for (int k = 0; k < 4; ++k) {
        int s0 = (int)(pk[k] & 0x1FFFFF);
        int s1 = (int)((pk[k] >> 21) & 0x1FFFFF);
        int s2 = (int)((pk[k] >> 42) & 0x1FFFFF);
        uint3 r0 = recs3[s0 / DC_C];
        uint3 r1 = recs3[s1 / DC_C];
        uint3 r2 = recs3[s2 / DC_C];
        float c0 = c2v_from_words(r0.x, r0.y, r0.z, s0 % DC_C);
        float c1 = c2v_from_words(r1.x, r1.y, r1.z, s1 % DC_C);
        float c2 = c2v_from_words(r2.x, r2.y, r2.z, s2 % DC_C);
        tot[k] = (c0 + c1) + c2;
    }
    efloat4 o;
    o.x = ll.x + tot[0];
    o.y = ll.y + tot[1];
    o.z = ll.z + tot[2];
    o.w = ll.w + tot[3];
    __builtin_nontemporal_store(o, &p4[i]);
}

// Final: posterior + hard decision, 4 vars/thread.
// out[0..n)=bits(f32 0/1), out[n..2n)=posterior.
__global__ __launch_bounds__(128) void final_kernel(
        const uint3* __restrict__ recs3,
        const eull2* __restrict__ pos64x2,
        const efloat4* __restrict__ llr4,
        float* __restrict__ out,
        int n4, int n) {
    int i = blockIdx.x * 128 + threadIdx.x;
    if (i >= n4) return;
    eull2 pk01 = __builtin_nontemporal_load(&pos64x2[i * 2 + 0]);
    eull2 pk23 = __builtin_nontemporal_load(&pos64x2[i * 2 + 1]);
    efloat4 ll = __builtin_nontemporal_load(&llr4[i]);
    unsigned long long pk[4] = {pk01.x, pk01.y, pk23.x, pk23.y};
    float llv[4] = {ll.x, ll.y, ll.z, ll.w};
    float post[4];
#pragma unroll
    for (int k = 0; k < 4; ++k) {
        int s0 = (int)(pk[k] & 0x1FFFFF);
        int s1 = (int)((pk[k] >> 21) & 0x1FFFFF);
        int s2 = (int)((pk[k] >> 42) & 0x1FFFFF);
        uint3 r0 = recs3[s0 / DC_C];
        uint3 r1 = recs3[s1 / DC_C];
        uint3 r2 = recs3[s2 / DC_C];
        float c0 = c2v_from_words(r0.x, r0.y, r0.z, s0 % DC_C);
        float c1 = c2v_from_words(r1.x, r1.y, r1.z, s1 % DC_C);
        float c2 = c2v_from_words(r2.x, r2.y, r2.z, s2 % DC_C);
        post[k] = llv[k] + ((c0 + c1) + c2);
    }
    efloat4 bits;
    bits.x = post[0] < 0.0f ? 1.0f : 0.0f;
    bits.y = post[1] < 0.0f ? 1.0f : 0.0f;
    bits.z = post[2] < 0.0f ? 1.0f : 0.0f;
    bits.w = post[3] < 0.0f ? 1.0f : 0.0f;
    efloat4 pst;
    pst.x = post[0]; pst.y = post[1]; pst.z = post[2]; pst.w = post[3];
    __builtin_nontemporal_store(bits, (efloat4*)(out + i * 4));
    __builtin_nontemporal_store(pst, (efloat4*)(out + n + i * 4));
}

extern "C" void kernel_launch(void* const* d_in, const int* in_sizes, int n_in,
                              void* d_out, int out_size, void* d_ws, size_t ws_size,
                              hipStream_t stream) {
    const float* llr      = (const float*)d_in[0];
    const float* beta     = (const float*)d_in[1];
    const float* alpha    = (const float*)d_in[2];
    const int*   edge_chk = (const int*)d_in[4];

    const int n  = in_sizes[0];       // 524288
    const int T  = in_sizes[1];       // 10
    const int E  = in_sizes[3];       // 1572864
    const int n_chk = E / DC_C;       // 262144

    // Workspace (rebuilt every call; ws re-poisoned between calls)
    char* ws = (char*)d_ws;
    unsigned int*       cnt8  = (unsigned int*)ws;                    // 128 KB @ 0
    unsigned long long* pos64 = (unsigned long long*)(ws + (1u << 20)); // 4 MB @ 1
    int*                vmap  = (int*)(ws + (5u << 20));              // 6 MB @ 5
    unsigned int*       recs  = (unsigned int*)(ws + (11u << 20));    // 3 MB @ 11
    float*              p     = (float*)(ws + (14u << 20));           // 2 MB @ 14

    hipMemsetAsync(cnt8, 0, (size_t)(n_chk / 8) * 4, stream);
    build_a<<<(n + 255) / 256, 256, 0, stream>>>(edge_chk, cnt8, pos64, n);
    {
        int chunks = (n + VCH - 1) / VCH;
        build_b<<<chunks * NRANGE, 256, 0, stream>>>(pos64, vmap, n, E);
    }
    const int n_chk2 = n_chk / 2;
    const int n4 = n / 4;
    for (int t = 0; t < T; ++t) {
        const float* src = (t == 0) ? llr : p;   // p_init == llr, c2v_0 == 0
        check_kernel<<<(n_chk2 + 127) / 128, 128, 0, stream>>>(
            src, (const euint4*)vmap, (euint2*)recs, beta, alpha,
            t, n_chk2, (t == 0) ? 1 : 0);
        if (t + 1 < T) {
            var_kernel<<<(n4 + 127) / 128, 128, 0, stream>>>(
                (const uint3*)recs, (const eull2*)pos64,
                (const efloat4*)llr, (efloat4*)p, n4);
        } else {
            final_kernel<<<(n4 + 127) / 128, 128, 0, stream>>>(
                (const uint3*)recs, (const eull2*)pos64,
                (const efloat4*)llr, (float*)d_out, n4, n);
        }
    }
}

// Round 10
// 378.631 us; speedup vs baseline: 1.0237x; 1.0237x over previous
//
#include <hip/hip_runtime.h>
#include <math.h>

#define DC_C 6
#define NRANGE 8          // slot ranges, aligned to blockIdx%8 -> XCD round-robin
#define VCH 2048          // vars per block-chunk in build_b

// Per-check compressed message record: 3 words per check.
// word0 = bits(Asp) = sprod*(relu(min2-b)-a)  [value on argmin edges]
// word1 = bits(Bsp) = sprod*(relu(min1-b)-a)  [value on other edges]
// word2 = masks: bits 0-5 amin, 8-13 negative-sign, 16-21 zero-sign
// c2v_j = sg_j * (amin_j ? Asp : Bsp), sg_j in {+1,-1,0}.

__device__ __forceinline__ float c2v_from_words(unsigned int aw, unsigned int bw,
                                                unsigned int mk, int j) {
    float val = ((mk >> j) & 1u) ? __uint_as_float(aw) : __uint_as_float(bw);
    float s = ((mk >> (16 + j)) & 1u) ? 0.0f
            : (((mk >> (8 + j)) & 1u) ? -1.0f : 1.0f);
    return s * val;
}

// Phase A: slot assignment (nibble-packed counters: 8 checks/word, 4b each;
// count <= 6 so nibbles never carry). 1.57M device atomics ~= 26 G/s floor
// (per-transaction memory-side write-through, ~32 B HBM each — R7-proven).
__global__ void build_a(const int* __restrict__ edge_chk,
                        unsigned int* __restrict__ cnt8,
                        unsigned long long* __restrict__ pos64,
                        int n) {
    int v = blockIdx.x * blockDim.x + threadIdx.x;
    if (v >= n) return;
    int c0 = edge_chk[v * 3 + 0];
    int c1 = edge_chk[v * 3 + 1];
    int c2 = edge_chk[v * 3 + 2];
    unsigned int sh0 = (c0 & 7) * 4, sh1 = (c1 & 7) * 4, sh2 = (c2 & 7) * 4;
    unsigned int o0 = atomicAdd(&cnt8[c0 >> 3], 1u << sh0);
    unsigned int o1 = atomicAdd(&cnt8[c1 >> 3], 1u << sh1);
    unsigned int o2 = atomicAdd(&cnt8[c2 >> 3], 1u << sh2);
    int j0 = (o0 >> sh0) & 0xF;
    int j1 = (o1 >> sh1) & 0xF;
    int j2 = (o2 >> sh2) & 0xF;
    unsigned long long s0 = (unsigned long long)(c0 * DC_C + j0);
    unsigned long long s1 = (unsigned long long)(c1 * DC_C + j1);
    unsigned long long s2 = (unsigned long long)(c2 * DC_C + j2);
    pos64[v] = s0 | (s1 << 21) | (s2 << 42);
}

// Phase B: invert pos64 -> vmap (slot -> variable). Only random write in the
// pipeline; range-partitioned so each vmap line is filled from one XCD
// (blockIdx%8 heuristic; perf-only, correctness-independent).
__global__ void build_b(const unsigned long long* __restrict__ pos64,
                        int* __restrict__ vmap,
                        int n, int E) {
    int r = blockIdx.x & (NRANGE - 1);
    int chunk = blockIdx.x >> 3;
    int lo = r * (E / NRANGE);
    int hi = lo + (E / NRANGE);
    int base = chunk * VCH;
#pragma unroll
    for (int rr = 0; rr < VCH / 256; ++rr) {
        int v = base + rr * 256 + threadIdx.x;
        if (v >= n) break;
        unsigned long long pk = pos64[v];
        int s0 = (int)(pk & 0x1FFFFF);
        int s1 = (int)((pk >> 21) & 0x1FFFFF);
        int s2 = (int)((pk >> 42) & 0x1FFFFF);
        if (s0 >= lo && s0 < hi) vmap[s0] = v;
        if (s1 >= lo && s1 < hi) vmap[s1] = v;
        if (s2 >= lo && s2 < hi) vmap[s2] = v;
    }
}

// Check-node update, 2 checks/thread (12 independent p-gathers in flight).
// All loads/stores plain (cache-resident): recs and p are producer->consumer
// buffers whose L2 residency across dispatches is the whole game (R9 lesson:
// NT hints here evict them and regress).
__global__ __launch_bounds__(256) void check_kernel(
        const float* __restrict__ p,        // llr at t=0
        const uint4* __restrict__ vmap4,    // 12 ints / pair = 3x uint4
        uint2* __restrict__ recs2,          // 6 words / pair = 3x uint2
        const float* __restrict__ beta,
        const float* __restrict__ alpha,
        int t, int n_chk2, int first) {
    int i = blockIdx.x * 256 + threadIdx.x;     // pair index
    if (i >= n_chk2) return;
    uint4 w0 = vmap4[i * 3 + 0];
    uint4 w1 = vmap4[i * 3 + 1];
    uint4 w2 = vmap4[i * 3 + 2];
    unsigned int w[12] = {w0.x, w0.y, w0.z, w0.w,
                          w1.x, w1.y, w1.z, w1.w,
                          w2.x, w2.y, w2.z, w2.w};
    float pv[12];
#pragma unroll
    for (int j = 0; j < 12; ++j) pv[j] = p[w[j]];

    float old_[12];
    if (first) {
#pragma unroll
        for (int j = 0; j < 12; ++j) old_[j] = 0.0f;
    } else {
        uint2 r01 = recs2[i * 3 + 0];
        uint2 r23 = recs2[i * 3 + 1];
        uint2 r45 = recs2[i * 3 + 2];
        // rec A = (r01.x, r01.y, r23.x); rec B = (r23.y, r45.x, r45.y)
#pragma unroll
        for (int j = 0; j < DC_C; ++j) {
            old_[j]     = c2v_from_words(r01.x, r01.y, r23.x, j);
            old_[6 + j] = c2v_from_words(r23.y, r45.x, r45.y, j);
        }
    }

    float b = beta[t];
    float a = alpha[t];
    unsigned int rw[6];
#pragma unroll
    for (int h = 0; h < 2; ++h) {
        float sprod = 1.0f;
        float m1 = INFINITY, m2 = INFINITY;
        float mg[DC_C];
        unsigned int ng = 0, zr = 0;
#pragma unroll
        for (int j = 0; j < DC_C; ++j) {
            float x = pv[h * 6 + j] - old_[h * 6 + j];
            float m = fabsf(x);
            mg[j] = m;
            if (x < 0.0f) { ng |= (1u << j); sprod = -sprod; }
            else if (x == 0.0f) { zr |= (1u << j); sprod = 0.0f; }
            if (m < m1) { m2 = m1; m1 = m; }
            else if (m < m2) { m2 = m; }
        }
        unsigned int am = 0;
#pragma unroll
        for (int j = 0; j < DC_C; ++j) am |= (mg[j] == m1) ? (1u << j) : 0u;
        // ties: multiple amin bits imply m2==m1 -> A==B, identical to the
        // reference's first-argmin rule.
        float A = fmaxf(m2 - b, 0.0f) - a;
        float B = fmaxf(m1 - b, 0.0f) - a;
        rw[h * 3 + 0] = __float_as_uint(sprod * A);
        rw[h * 3 + 1] = __float_as_uint(sprod * B);
        rw[h * 3 + 2] = am | (ng << 8) | (zr << 16);
    }
    recs2[i * 3 + 0] = make_uint2(rw[0], rw[1]);
    recs2[i * 3 + 1] = make_uint2(rw[2], rw[3]);
    recs2[i * 3 + 2] = make_uint2(rw[4], rw[5]);
}

// Variable-node update, 4 vars/thread (12 independent rec-gathers in flight).
__global__ __launch_bounds__(256) void var_kernel(
        const uint3* __restrict__ recs3,
        const ulonglong2* __restrict__ pos64x2,
        const float4* __restrict__ llr4,
        float4* __restrict__ p4,
        int n4) {
    int i = blockIdx.x * 256 + threadIdx.x;
    if (i >= n4) return;
    ulonglong2 pk01 = pos64x2[i * 2 + 0];
    ulonglong2 pk23 = pos64x2[i * 2 + 1];
    float4 ll = llr4[i];
    unsigned long long pk[4] = {pk01.x, pk01.y, pk23.x, pk23.y};
    float tot[4];
#pragma unroll
    for (int k = 0; k < 4; ++k) {
        int s0 = (int)(pk[k] & 0x1FFFFF);
        int s1 = (int)((pk[k] >> 21) & 0x1FFFFF);
        int s2 = (int)((pk[k] >> 42) & 0x1FFFFF);
        uint3 r0 = recs3[s0 / DC_C];
        uint3 r1 = recs3[s1 / DC_C];
        uint3 r2 = recs3[s2 / DC_C];
        float c0 = c2v_from_words(r0.x, r0.y, r0.z, s0 % DC_C);
        float c1 = c2v_from_words(r1.x, r1.y, r1.z, s1 % DC_C);
        float c2 = c2v_from_words(r2.x, r2.y, r2.z, s2 % DC_C);
        tot[k] = (c0 + c1) + c2;
    }
    p4[i] = make_float4(ll.x + tot[0], ll.y + tot[1],
                        ll.z + tot[2], ll.w + tot[3]);
}

// Final: posterior + hard decision, 4 vars/thread.
// out[0..n)=bits(f32 0/1), out[n..2n)=posterior.
__global__ __launch_bounds__(256) void final_kernel(
        const uint3* __restrict__ recs3,
        const ulonglong2* __restrict__ pos64x2,
        const float4* __restrict__ llr4,
        float* __restrict__ out,
        int n4, int n) {
    int i = blockIdx.x * 256 + threadIdx.x;
    if (i >= n4) return;
    ulonglong2 pk01 = pos64x2[i * 2 + 0];
    ulonglong2 pk23 = pos64x2[i * 2 + 1];
    float4 ll = llr4[i];
    unsigned long long pk[4] = {pk01.x, pk01.y, pk23.x, pk23.y};
    float llv[4] = {ll.x, ll.y, ll.z, ll.w};
    float post[4];
#pragma unroll
    for (int k = 0; k < 4; ++k) {
        int s0 = (int)(pk[k] & 0x1FFFFF);
        int s1 = (int)((pk[k] >> 21) & 0x1FFFFF);
        int s2 = (int)((pk[k] >> 42) & 0x1FFFFF);
        uint3 r0 = recs3[s0 / DC_C];
        uint3 r1 = recs3[s1 / DC_C];
        uint3 r2 = recs3[s2 / DC_C];
        float c0 = c2v_from_words(r0.x, r0.y, r0.z, s0 % DC_C);
        float c1 = c2v_from_words(r1.x, r1.y, r1.z, s1 % DC_C);
        float c2 = c2v_from_words(r2.x, r2.y, r2.z, s2 % DC_C);
        post[k] = llv[k] + ((c0 + c1) + c2);
    }
    *(float4*)(out + i * 4) = make_float4(post[0] < 0.0f ? 1.0f : 0.0f,
                                          post[1] < 0.0f ? 1.0f : 0.0f,
                                          post[2] < 0.0f ? 1.0f : 0.0f,
                                          post[3] < 0.0f ? 1.0f : 0.0f);
    *(float4*)(out + n + i * 4) = make_float4(post[0], post[1],
                                              post[2], post[3]);
}

extern "C" void kernel_launch(void* const* d_in, const int* in_sizes, int n_in,
                              void* d_out, int out_size, void* d_ws, size_t ws_size,
                              hipStream_t stream) {
    const float* llr      = (const float*)d_in[0];
    const float* beta     = (const float*)d_in[1];
    const float* alpha    = (const float*)d_in[2];
    const int*   edge_chk = (const int*)d_in[4];

    const int n  = in_sizes[0];       // 524288
    const int T  = in_sizes[1];       // 10
    const int E  = in_sizes[3];       // 1572864
    const int n_chk = E / DC_C;       // 262144

    // Workspace (rebuilt every call; ws re-poisoned between calls)
    char* ws = (char*)d_ws;
    unsigned int*       cnt8  = (unsigned int*)ws;                    // 128 KB @ 0
    unsigned long long* pos64 = (unsigned long long*)(ws + (1u << 20)); // 4 MB @ 1
    int*                vmap  = (int*)(ws + (5u << 20));              // 6 MB @ 5
    unsigned int*       recs  = (unsigned int*)(ws + (11u << 20));    // 3 MB @ 11
    float*              p     = (float*)(ws + (14u << 20));           // 2 MB @ 14

    hipMemsetAsync(cnt8, 0, (size_t)(n_chk / 8) * 4, stream);
    build_a<<<(n + 255) / 256, 256, 0, stream>>>(edge_chk, cnt8, pos64, n);
    {
        int chunks = (n + VCH - 1) / VCH;
        build_b<<<chunks * NRANGE, 256, 0, stream>>>(pos64, vmap, n, E);
    }
    const int n_chk2 = n_chk / 2;
    const int n4 = n / 4;
    for (int t = 0; t < T; ++t) {
        const float* src = (t == 0) ? llr : p;   // p_init == llr, c2v_0 == 0
        check_kernel<<<(n_chk2 + 255) / 256, 256, 0, stream>>>(
            src, (const uint4*)vmap, (uint2*)recs, beta, alpha,
            t, n_chk2, (t == 0) ? 1 : 0);
        if (t + 1 < T) {
            var_kernel<<<(n4 + 255) / 256, 256, 0, stream>>>(
                (const uint3*)recs, (const ulonglong2*)pos64,
                (const float4*)llr, (float4*)p, n4);
        } else {
            final_kernel<<<(n4 + 255) / 256, 256, 0, stream>>>(
                (const uint3*)recs, (const ulonglong2*)pos64,
                (const float4*)llr, (float*)d_out, n4, n);
        }
    }
}

// Round 11
// 366.014 us; speedup vs baseline: 1.0590x; 1.0345x over previous
//
#include <hip/hip_runtime.h>
#include <math.h>

#define DC_C 6
#define NRANGE 8          // slot ranges, aligned to blockIdx%8 -> XCD round-robin
#define VCH 2048          // vars per block-chunk in build_b

// Per-check compressed message record (12 B = uint3, one dwordx3 gather).
// x = bits(Asp) = sprod*(relu(min2-b)-a)  [value on argmin edges]
// y = bits(Bsp) = sprod*(relu(min1-b)-a)  [value on other edges]
// z = masks: bits 0-5 amin, 8-13 negative-sign, 16-21 zero-sign
// c2v_j = sg_j * (amin_j ? Asp : Bsp), sg_j in {+1,-1,0}.

__device__ __forceinline__ float c2v_from_rec(uint3 r, int j) {
    float val = ((r.z >> j) & 1u) ? __uint_as_float(r.x) : __uint_as_float(r.y);
    float s = ((r.z >> (16 + j)) & 1u) ? 0.0f
            : (((r.z >> (8 + j)) & 1u) ? -1.0f : 1.0f);
    return s * val;
}

// Phase A: slot assignment (nibble-packed counters: 8 checks/word, 4b each;
// count <= 6 so nibbles never carry). Pinned at the device-atomic floor:
// 1.57M atomics x ~34 B HBM write-through each = 53 MB at ~940 GB/s = ~61 us.
// Invariant under occupancy, pipelining, and counter-footprint changes
// (R3/R4/R7 evidence) — accepted structural cost.
__global__ void build_a(const int* __restrict__ edge_chk,
                        unsigned int* __restrict__ cnt8,
                        unsigned long long* __restrict__ pos64,
                        int n) {
    int v = blockIdx.x * blockDim.x + threadIdx.x;
    if (v >= n) return;
    int c0 = edge_chk[v * 3 + 0];
    int c1 = edge_chk[v * 3 + 1];
    int c2 = edge_chk[v * 3 + 2];
    unsigned int sh0 = (c0 & 7) * 4, sh1 = (c1 & 7) * 4, sh2 = (c2 & 7) * 4;
    unsigned int o0 = atomicAdd(&cnt8[c0 >> 3], 1u << sh0);
    unsigned int o1 = atomicAdd(&cnt8[c1 >> 3], 1u << sh1);
    unsigned int o2 = atomicAdd(&cnt8[c2 >> 3], 1u << sh2);
    int j0 = (o0 >> sh0) & 0xF;
    int j1 = (o1 >> sh1) & 0xF;
    int j2 = (o2 >> sh2) & 0xF;
    unsigned long long s0 = (unsigned long long)(c0 * DC_C + j0);
    unsigned long long s1 = (unsigned long long)(c1 * DC_C + j1);
    unsigned long long s2 = (unsigned long long)(c2 * DC_C + j2);
    pos64[v] = s0 | (s1 << 21) | (s2 << 42);
}

// Phase B: invert pos64 -> vmap (slot -> variable). Only random write in the
// pipeline; range-partitioned so each vmap line is filled from one XCD
// (blockIdx%8 heuristic; perf-only, correctness-independent).
__global__ void build_b(const unsigned long long* __restrict__ pos64,
                        int* __restrict__ vmap,
                        int n, int E) {
    int r = blockIdx.x & (NRANGE - 1);
    int chunk = blockIdx.x >> 3;
    int lo = r * (E / NRANGE);
    int hi = lo + (E / NRANGE);
    int base = chunk * VCH;
#pragma unroll
    for (int rr = 0; rr < VCH / 256; ++rr) {
        int v = base + rr * 256 + threadIdx.x;
        if (v >= n) break;
        unsigned long long pk = pos64[v];
        int s0 = (int)(pk & 0x1FFFFF);
        int s1 = (int)((pk >> 21) & 0x1FFFFF);
        int s2 = (int)((pk >> 42) & 0x1FFFFF);
        if (s0 >= lo && s0 < hi) vmap[s0] = v;
        if (s1 >= lo && s1 < hi) vmap[s1] = v;
        if (s2 >= lo && s2 < hi) vmap[s2] = v;
    }
}

// Check-node update, 1 check/thread (measured optimum: R10's 2/thread halves
// block count to 2/CU and regresses; R3's extra waves are neutral).
// Coalesced: vmap (3x int2), old record, new record. Random: 6 p-gathers
// from a 2 MB per-XCD-L2-resident array. Plain loads/stores only (R9: NT
// hints on producer->consumer buffers defeat cross-dispatch L2 reuse).
__global__ void check_kernel(const float* __restrict__ p,     // llr at t=0
                             const int* __restrict__ vmap,
                             uint3* __restrict__ recs,
                             const float* __restrict__ beta,
                             const float* __restrict__ alpha,
                             int t, int n_chk, int first) {
    int c = blockIdx.x * blockDim.x + threadIdx.x;
    if (c >= n_chk) return;
    int base = c * DC_C;
    int2 w01 = *(const int2*)(vmap + base);
    int2 w23 = *(const int2*)(vmap + base + 2);
    int2 w45 = *(const int2*)(vmap + base + 4);
    int w[DC_C] = {w01.x, w01.y, w23.x, w23.y, w45.x, w45.y};
    float pv[DC_C];
#pragma unroll
    for (int j = 0; j < DC_C; ++j) pv[j] = p[w[j]];

    float old_[DC_C];
    if (first) {
#pragma unroll
        for (int j = 0; j < DC_C; ++j) old_[j] = 0.0f;
    } else {
        uint3 rec = recs[c];
#pragma unroll
        for (int j = 0; j < DC_C; ++j) old_[j] = c2v_from_rec(rec, j);
    }

    float b = beta[t];
    float a = alpha[t];
    float sprod = 1.0f;
    float m1 = INFINITY, m2 = INFINITY;
    float mg[DC_C];
    unsigned int ng = 0, zr = 0;
#pragma unroll
    for (int j = 0; j < DC_C; ++j) {
        float x = pv[j] - old_[j];
        float m = fabsf(x);
        mg[j] = m;
        if (x < 0.0f) { ng |= (1u << j); sprod = -sprod; }
        else if (x == 0.0f) { zr |= (1u << j); sprod = 0.0f; }
        if (m < m1) { m2 = m1; m1 = m; }
        else if (m < m2) { m2 = m; }
    }
    unsigned int am = 0;
#pragma unroll
    for (int j = 0; j < DC_C; ++j) am |= (mg[j] == m1) ? (1u << j) : 0u;
    // ties: multiple amin bits imply m2==m1 -> A==B, identical to the
    // reference's first-argmin rule.
    float A = fmaxf(m2 - b, 0.0f) - a;
    float B = fmaxf(m1 - b, 0.0f) - a;
    recs[c] = make_uint3(__float_as_uint(sprod * A),
                         __float_as_uint(sprod * B),
                         am | (ng << 8) | (zr << 16));
}

// Variable-node update, 2 vars/thread (measured optimum).
// Coalesced: pos64 (ulonglong2), llr (float2), p write (float2).
// Random: 6 record gathers from 3 MB L2-resident recs.
__global__ void var_kernel(const uint3* __restrict__ recs,
                           const unsigned long long* __restrict__ pos64,
                           const float* __restrict__ llr,
                           float* __restrict__ p,
                           int n2) {       // n/2
    int i = blockIdx.x * blockDim.x + threadIdx.x;
    if (i >= n2) return;
    ulonglong2 pk2 = *(const ulonglong2*)(pos64 + i * 2);
    float2 ll = *(const float2*)(llr + i * 2);
    int a0 = (int)(pk2.x & 0x1FFFFF);
    int a1 = (int)((pk2.x >> 21) & 0x1FFFFF);
    int a2 = (int)((pk2.x >> 42) & 0x1FFFFF);
    int b0 = (int)(pk2.y & 0x1FFFFF);
    int b1 = (int)((pk2.y >> 21) & 0x1FFFFF);
    int b2 = (int)((pk2.y >> 42) & 0x1FFFFF);
    uint3 ra0 = recs[a0 / DC_C];
    uint3 ra1 = recs[a1 / DC_C];
    uint3 ra2 = recs[a2 / DC_C];
    uint3 rb0 = recs[b0 / DC_C];
    uint3 rb1 = recs[b1 / DC_C];
    uint3 rb2 = recs[b2 / DC_C];
    float ca0 = c2v_from_rec(ra0, a0 % DC_C);
    float ca1 = c2v_from_rec(ra1, a1 % DC_C);
    float ca2 = c2v_from_rec(ra2, a2 % DC_C);
    float cb0 = c2v_from_rec(rb0, b0 % DC_C);
    float cb1 = c2v_from_rec(rb1, b1 % DC_C);
    float cb2 = c2v_from_rec(rb2, b2 % DC_C);
    float2 o;
    o.x = ll.x + ((ca0 + ca1) + ca2);
    o.y = ll.y + ((cb0 + cb1) + cb2);
    *(float2*)(p + i * 2) = o;
}

// Final: posterior + hard decision, 2 vars/thread.
// out[0..n)=bits(f32 0/1), out[n..2n)=posterior.
__global__ void final_kernel(const uint3* __restrict__ recs,
                             const unsigned long long* __restrict__ pos64,
                             const float* __restrict__ llr,
                             float* __restrict__ out,
                             int n2, int n) {
    int i = blockIdx.x * blockDim.x + threadIdx.x;
    if (i >= n2) return;
    ulonglong2 pk2 = *(const ulonglong2*)(pos64 + i * 2);
    float2 ll = *(const float2*)(llr + i * 2);
    int a0 = (int)(pk2.x & 0x1FFFFF);
    int a1 = (int)((pk2.x >> 21) & 0x1FFFFF);
    int a2 = (int)((pk2.x >> 42) & 0x1FFFFF);
    int b0 = (int)(pk2.y & 0x1FFFFF);
    int b1 = (int)((pk2.y >> 21) & 0x1FFFFF);
    int b2 = (int)((pk2.y >> 42) & 0x1FFFFF);
    uint3 ra0 = recs[a0 / DC_C];
    uint3 ra1 = recs[a1 / DC_C];
    uint3 ra2 = recs[a2 / DC_C];
    uint3 rb0 = recs[b0 / DC_C];
    uint3 rb1 = recs[b1 / DC_C];
    uint3 rb2 = recs[b2 / DC_C];
    float pa = ll.x + ((c2v_from_rec(ra0, a0 % DC_C)
                      + c2v_from_rec(ra1, a1 % DC_C))
                      + c2v_from_rec(ra2, a2 % DC_C));
    float pb = ll.y + ((c2v_from_rec(rb0, b0 % DC_C)
                      + c2v_from_rec(rb1, b1 % DC_C))
                      + c2v_from_rec(rb2, b2 % DC_C));
    float2 bits, post;
    bits.x = (pa < 0.0f) ? 1.0f : 0.0f;
    bits.y = (pb < 0.0f) ? 1.0f : 0.0f;
    post.x = pa;
    post.y = pb;
    *(float2*)(out + i * 2) = bits;
    *(float2*)(out + n + i * 2) = post;
}

extern "C" void kernel_launch(void* const* d_in, const int* in_sizes, int n_in,
                              void* d_out, int out_size, void* d_ws, size_t ws_size,
                              hipStream_t stream) {
    const float* llr      = (const float*)d_in[0];
    const float* beta     = (const float*)d_in[1];
    const float* alpha    = (const float*)d_in[2];
    const int*   edge_chk = (const int*)d_in[4];

    const int n  = in_sizes[0];       // 524288
    const int T  = in_sizes[1];       // 10
    const int E  = in_sizes[3];       // 1572864
    const int n_chk = E / DC_C;       // 262144

    // Workspace (rebuilt every call; ws re-poisoned between calls)
    char* ws = (char*)d_ws;
    unsigned int*       cnt8  = (unsigned int*)ws;                    // 128 KB @ 0
    unsigned long long* pos64 = (unsigned long long*)(ws + (1u << 20)); // 4 MB @ 1
    int*                vmap  = (int*)(ws + (5u << 20));              // 6 MB @ 5
    unsigned int*       recs  = (unsigned int*)(ws + (11u << 20));    // 3 MB @ 11
    float*              p     = (float*)(ws + (14u << 20));           // 2 MB @ 14

    hipMemsetAsync(cnt8, 0, (size_t)(n_chk / 8) * 4, stream);
    build_a<<<(n + 255) / 256, 256, 0, stream>>>(edge_chk, cnt8, pos64, n);
    {
        int chunks = (n + VCH - 1) / VCH;
        build_b<<<chunks * NRANGE, 256, 0, stream>>>(pos64, vmap, n, E);
    }
    for (int t = 0; t < T; ++t) {
        const float* src = (t == 0) ? llr : p;   // p_init == llr, c2v_0 == 0
        check_kernel<<<(n_chk + 255) / 256, 256, 0, stream>>>(
            src, vmap, (uint3*)recs, beta, alpha, t, n_chk, (t == 0) ? 1 : 0);
        if (t + 1 < T) {
            var_kernel<<<(n / 2 + 255) / 256, 256, 0, stream>>>(
                (const uint3*)recs, pos64, llr, p, n / 2);
        } else {
            final_kernel<<<(n / 2 + 255) / 256, 256, 0, stream>>>(
                (const uint3*)recs, pos64, llr, (float*)d_out, n / 2, n);
        }
    }
}